// Round 4
// baseline (457.078 us; speedup 1.0000x reference)
//
#include <hip/hip_runtime.h>

typedef unsigned int uint;
typedef unsigned short ushort;

typedef __attribute__((ext_vector_type(8))) short bf16x8;
typedef __attribute__((ext_vector_type(4))) float f32x4;

#define TOK 256
#define OUTF 11008
#define INF 4096
#define BN 32
#define NTILES 344  // OUTF / BN

__device__ __constant__ float NF4_TBL[16] = {
    -1.0f, -0.6961928009986877f, -0.5250730514526367f, -0.39491748809814453f,
    -0.28444138169288635f, -0.18477343022823334f, -0.09105003625154495f, 0.0f,
    0.07958029955625534f, 0.16093020141124725f, 0.24611230194568634f,
    0.33791524171829224f, 0.44070982933044434f, 0.5626170039176941f,
    0.7229568362236023f, 1.0f};

__device__ __forceinline__ ushort f2bf(float f) {
  return (ushort)((__float_as_uint(f) + 0x8000u) >> 16);
}

// dequant 2 nf4 codes -> packed 2x bf16 (low = first code); table lives in lanes 0..15
__device__ __forceinline__ uint dq2(int ca, int cb, float amax, int tbits) {
  float fa = __int_as_float(__builtin_amdgcn_ds_bpermute(ca << 2, tbits)) * amax;
  float fb = __int_as_float(__builtin_amdgcn_ds_bpermute(cb << 2, tbits)) * amax;
  uint ua = (__float_as_uint(fa) + 0x8000u) >> 16;
  uint ub = (__float_as_uint(fb) + 0x8000u) & 0xffff0000u;
  return ua | ub;
}

// 8 codes (2x int4) -> one MFMA b-frag (8 bf16)
__device__ __forceinline__ bf16x8 dq8(int4 c0, int4 c1, float amax, int tbits) {
  union { uint4 u; bf16x8 b; } cv;
  cv.u.x = dq2(c0.x, c0.y, amax, tbits);
  cv.u.y = dq2(c0.z, c0.w, amax, tbits);
  cv.u.z = dq2(c1.x, c1.y, amax, tbits);
  cv.u.w = dq2(c1.z, c1.w, amax, tbits);
  return cv.b;
}

// kernel 1: x fp32 -> bf16 (float4) ; lora_B fp32 [OUTF,16] -> bf16 [OUTF,64] zero-padded
__global__ void prep_kernel(const float4* __restrict__ x4, const float4* __restrict__ lB4,
                            ushort4* __restrict__ xbf4, ushort4* __restrict__ lBbf4) {
  const int stride = gridDim.x * blockDim.x;
  for (int idx = blockIdx.x * blockDim.x + threadIdx.x; idx < TOK * INF / 4; idx += stride) {
    float4 v = x4[idx];
    ushort4 o;
    o.x = f2bf(v.x); o.y = f2bf(v.y); o.z = f2bf(v.z); o.w = f2bf(v.w);
    xbf4[idx] = o;
  }
  for (int idx = blockIdx.x * blockDim.x + threadIdx.x; idx < OUTF * 16; idx += stride) {
    int n = idx >> 4, jq = idx & 15;
    ushort4 o = {0, 0, 0, 0};
    if (jq < 4) {
      float4 v = lB4[n * 4 + jq];
      o.x = f2bf(v.x); o.y = f2bf(v.y); o.z = f2bf(v.z); o.w = f2bf(v.w);
    }
    lBbf4[idx] = o;
  }
}

// kernel 2: xa2[m][j] = bf16( 2 * sum_k x[m][k]*lora_A[j][k] ), [TOK,64] zero-padded
__global__ __launch_bounds__(1024)
void xa_kernel(const float* __restrict__ x, const float* __restrict__ lA,
               ushort* __restrict__ xa2) {
  const int m = blockIdx.x;
  const int t = threadIdx.x;
  const float4* x4 = (const float4*)(x + (size_t)m * INF);
  const float4* lA4 = (const float4*)lA;
  float4 xv = x4[t];
  float acc[16];
#pragma unroll
  for (int j = 0; j < 16; ++j) {
    float4 a = lA4[j * (INF / 4) + t];
    acc[j] = xv.x * a.x + xv.y * a.y + xv.z * a.z + xv.w * a.w;
  }
#pragma unroll
  for (int j = 0; j < 16; ++j)
#pragma unroll
    for (int s = 32; s > 0; s >>= 1) acc[j] += __shfl_xor(acc[j], s, 64);
  __shared__ float red[16][16];
  const int w = t >> 6, l = t & 63;
  if (l == 0) {
#pragma unroll
    for (int j = 0; j < 16; ++j) red[w][j] = acc[j];
  }
  __syncthreads();
  if (t < 64) {
    ushort v = 0;
    if (t < 16) {
      float s = 0.f;
#pragma unroll
      for (int w2 = 0; w2 < 16; ++w2) s += red[w2][t];
      v = f2bf(2.0f * s);
    }
    xa2[m * 64 + t] = v;
  }
}

// kernel 3: barrier-free fused dequant GEMM. No LDS: each lane loads its own
// A-frag (16B from L2-resident xbf) and dequants its own B-frag in-register.
__global__ __launch_bounds__(256, 3)
void gemm_kernel(const int* __restrict__ qc, const float* __restrict__ am,
                 const ushort* __restrict__ xbf, const ushort* __restrict__ lBbf,
                 const ushort* __restrict__ xa2, float* __restrict__ dest,
                 int nst) {
  const int tid = threadIdx.x;
  const int w = tid >> 6;
  const int l = tid & 63;
  const int chunk = l >> 4;   // 0..3
  const int rlo = l & 15;
  const int split = blockIdx.x / NTILES;
  const int ntile = blockIdx.x - split * NTILES;
  const int n0 = ntile * BN;
  const int k0 = split * nst * 32;

  const int tbits = __float_as_int(NF4_TBL[rlo]);  // lanes 0..15 of each group hold the table

  // per-lane base pointers
  const ushort* aptr[4];
#pragma unroll
  for (int mt = 0; mt < 4; ++mt)
    aptr[mt] = xbf + (size_t)(w * 64 + mt * 16 + rlo) * INF + chunk * 8;
  int col[2];
  const int* qptr[2];
  const float* amptr[2];
#pragma unroll
  for (int nt = 0; nt < 2; ++nt) {
    col[nt] = n0 + nt * 16 + rlo;
    qptr[nt] = qc + (size_t)col[nt] * INF + chunk * 8;
    amptr[nt] = am + (size_t)col[nt] * 64;
  }

  f32x4 acc[4][2];
#pragma unroll
  for (int mt = 0; mt < 4; ++mt)
#pragma unroll
    for (int nt = 0; nt < 2; ++nt) acc[mt][nt] = (f32x4){0.f, 0.f, 0.f, 0.f};

  // pipeline stage: loads for step s
  bf16x8 a_c[4];
  int4 c0_c[2], c1_c[2];
  float ax_c[2];
#pragma unroll
  for (int mt = 0; mt < 4; ++mt) a_c[mt] = *(const bf16x8*)(aptr[mt] + k0);
#pragma unroll
  for (int nt = 0; nt < 2; ++nt) {
    const int4* qp = (const int4*)(qptr[nt] + k0);
    c0_c[nt] = qp[0];
    c1_c[nt] = qp[1];
    ax_c[nt] = amptr[nt][k0 >> 6];
  }

#pragma unroll 2
  for (int s = 0; s < nst; ++s) {
    const int k = k0 + s * 32;
    bf16x8 a_n[4];
    int4 c0_n[2], c1_n[2];
    float ax_n[2];
    if (s + 1 < nst) {
      const int kn = k + 32;
#pragma unroll
      for (int mt = 0; mt < 4; ++mt) a_n[mt] = *(const bf16x8*)(aptr[mt] + kn);
#pragma unroll
      for (int nt = 0; nt < 2; ++nt) {
        const int4* qp = (const int4*)(qptr[nt] + kn);
        c0_n[nt] = qp[0];
        c1_n[nt] = qp[1];
        ax_n[nt] = amptr[nt][kn >> 6];
      }
    }
    bf16x8 b[2];
#pragma unroll
    for (int nt = 0; nt < 2; ++nt) b[nt] = dq8(c0_c[nt], c1_c[nt], ax_c[nt], tbits);
#pragma unroll
    for (int mt = 0; mt < 4; ++mt)
#pragma unroll
      for (int nt = 0; nt < 2; ++nt)
        acc[mt][nt] = __builtin_amdgcn_mfma_f32_16x16x32_bf16(a_c[mt], b[nt], acc[mt][nt], 0, 0, 0);
    if (s + 1 < nst) {
#pragma unroll
      for (int mt = 0; mt < 4; ++mt) a_c[mt] = a_n[mt];
#pragma unroll
      for (int nt = 0; nt < 2; ++nt) {
        c0_c[nt] = c0_n[nt]; c1_c[nt] = c1_n[nt]; ax_c[nt] = ax_n[nt];
      }
    }
  }

  if (split == 0) {
    // lora K-extension: one 32-wide k-step; A from xa2 [TOK,64], B from lBbf [OUTF,64]
    bf16x8 a_l[4], b_l[2];
#pragma unroll
    for (int mt = 0; mt < 4; ++mt)
      a_l[mt] = *(const bf16x8*)(xa2 + (size_t)(w * 64 + mt * 16 + rlo) * 64 + chunk * 8);
#pragma unroll
    for (int nt = 0; nt < 2; ++nt)
      b_l[nt] = *(const bf16x8*)(lBbf + (size_t)col[nt] * 64 + chunk * 8);
#pragma unroll
    for (int mt = 0; mt < 4; ++mt)
#pragma unroll
      for (int nt = 0; nt < 2; ++nt)
        acc[mt][nt] = __builtin_amdgcn_mfma_f32_16x16x32_bf16(a_l[mt], b_l[nt], acc[mt][nt], 0, 0, 0);
  }

  // epilogue: C/D layout col=lane&15, row=(lane>>4)*4+reg; each split owns a slice
  float* dst = dest + (size_t)split * TOK * OUTF;
#pragma unroll
  for (int mt = 0; mt < 4; ++mt) {
#pragma unroll
    for (int nt = 0; nt < 2; ++nt) {
      int c = n0 + nt * 16 + rlo;
#pragma unroll
      for (int r = 0; r < 4; ++r) {
        int row = w * 64 + mt * 16 + (l >> 4) * 4 + r;
        dst[(size_t)row * OUTF + c] = acc[mt][nt][r];
      }
    }
  }
}

// kernel 4: sum K-split partials -> out
__global__ void reduce_kernel(const float4* __restrict__ part, float4* __restrict__ out,
                              int ks) {
  const int QN = TOK * OUTF / 4;
  int i = blockIdx.x * blockDim.x + threadIdx.x;
  if (i < QN) {
    float4 s = part[i];
    for (int s2 = 1; s2 < ks; ++s2) {
      float4 p = part[(size_t)s2 * QN + i];
      s.x += p.x; s.y += p.y; s.z += p.z; s.w += p.w;
    }
    out[i] = s;
  }
}

extern "C" void kernel_launch(void* const* d_in, const int* in_sizes, int n_in,
                              void* d_out, int out_size, void* d_ws, size_t ws_size,
                              hipStream_t stream) {
  const float* x = (const float*)d_in[0];
  const int* qc = (const int*)d_in[1];
  const float* am = (const float*)d_in[2];
  const float* lA = (const float*)d_in[3];
  const float* lB = (const float*)d_in[4];
  float* out = (float*)d_out;

  const size_t off_lB = (size_t)TOK * INF * 2;            // 2 MB
  const size_t off_xa2 = off_lB + (size_t)OUTF * 64 * 2;  // +1.34 MB
  const size_t off_part = off_xa2 + (size_t)TOK * 64 * 2; // +32 KB (16B aligned)
  const size_t part_bytes = (size_t)TOK * OUTF * 4;       // 11.27 MB per split

  ushort* xbf = (ushort*)d_ws;
  ushort* lBbf = (ushort*)((char*)d_ws + off_lB);
  ushort* xa2 = (ushort*)((char*)d_ws + off_xa2);
  float* part = (float*)((char*)d_ws + off_part);

  int ks = 1;
  if (ws_size >= off_part + 4 * part_bytes) ks = 4;
  else if (ws_size >= off_part + 2 * part_bytes) ks = 2;
  float* dest = (ks == 1) ? out : part;

  prep_kernel<<<2048, 256, 0, stream>>>((const float4*)x, (const float4*)lB,
                                        (ushort4*)xbf, (ushort4*)lBbf);
  xa_kernel<<<TOK, 1024, 0, stream>>>(x, lA, xa2);
  gemm_kernel<<<NTILES * ks, 256, 0, stream>>>(qc, am, xbf, lBbf, xa2, dest, 128 / ks);
  if (ks > 1)
    reduce_kernel<<<(TOK * OUTF / 4 + 255) / 256, 256, 0, stream>>>((const float4*)part,
                                                                    (float4*)out, ks);
}

// Round 5
// 371.239 us; speedup vs baseline: 1.2312x; 1.2312x over previous
//
#include <hip/hip_runtime.h>
#include <hip/hip_fp16.h>

typedef unsigned int uint;
typedef unsigned short ushort;

typedef __attribute__((ext_vector_type(8))) _Float16 f16x8;
typedef __attribute__((ext_vector_type(4))) float f32x4;

#define TOK 256
#define OUTF 11008
#define INF 4096
#define BM 256
#define BN 64
#define NT2 172  // OUTF / BN

__device__ __constant__ float NF4_TBL[16] = {
    -1.0f, -0.6961928009986877f, -0.5250730514526367f, -0.39491748809814453f,
    -0.28444138169288635f, -0.18477343022823334f, -0.09105003625154495f, 0.0f,
    0.07958029955625534f, 0.16093020141124725f, 0.24611230194568634f,
    0.33791524171829224f, 0.44070982933044434f, 0.5626170039176941f,
    0.7229568362236023f, 1.0f};

__device__ __forceinline__ ushort f2h(float f) {
  return __half_as_ushort(__float2half(f));
}

// async global->LDS, 16B per lane; lds base wave-uniform + lane*16 (global addr is per-lane)
__device__ __forceinline__ void async_cp16(const void* g, void* l) {
  __builtin_amdgcn_global_load_lds(
      (const __attribute__((address_space(1))) uint*)g,
      (__attribute__((address_space(3))) uint*)l, 16, 0, 0);
}

// kernel 1 (fused prep): pack q int32->nibbles; x fp32->f16; lora_B fp32 [OUTF,16]->f16 [OUTF,64] padded
__global__ void prep_kernel(const int4* __restrict__ qc4, uint* __restrict__ pk,
                            const float4* __restrict__ x4, ushort4* __restrict__ xh4,
                            const float4* __restrict__ lB4, ushort4* __restrict__ lBh4) {
  const int stride = gridDim.x * blockDim.x;
  const int t0 = blockIdx.x * blockDim.x + threadIdx.x;
  for (int d = t0; d < OUTF * INF / 8; d += stride) {
    int4 a = qc4[2 * d];
    int4 b = qc4[2 * d + 1];
    pk[d] = (uint)(a.x & 15) | ((uint)(a.y & 15) << 4) | ((uint)(a.z & 15) << 8) |
            ((uint)(a.w & 15) << 12) | ((uint)(b.x & 15) << 16) | ((uint)(b.y & 15) << 20) |
            ((uint)(b.z & 15) << 24) | ((uint)(b.w & 15) << 28);
  }
  for (int i = t0; i < TOK * INF / 4; i += stride) {
    float4 v = x4[i];
    ushort4 o;
    o.x = f2h(v.x); o.y = f2h(v.y); o.z = f2h(v.z); o.w = f2h(v.w);
    xh4[i] = o;
  }
  for (int i = t0; i < OUTF * 16; i += stride) {
    int n = i >> 4, jq = i & 15;
    ushort4 o = {0, 0, 0, 0};
    if (jq < 4) {
      float4 v = lB4[n * 4 + jq];
      o.x = f2h(v.x); o.y = f2h(v.y); o.z = f2h(v.z); o.w = f2h(v.w);
    }
    lBh4[i] = o;
  }
}

// kernel 2: xa2[m][j] = f16( 2 * sum_k x[m][k]*lora_A[j][k] ), [TOK,64] zero-padded
__global__ __launch_bounds__(1024)
void xa_kernel(const float* __restrict__ x, const float* __restrict__ lA,
               ushort* __restrict__ xa2) {
  const int m = blockIdx.x;
  const int t = threadIdx.x;
  const float4* x4 = (const float4*)(x + (size_t)m * INF);
  const float4* lA4 = (const float4*)lA;
  float4 xv = x4[t];
  float acc[16];
#pragma unroll
  for (int j = 0; j < 16; ++j) {
    float4 a = lA4[j * (INF / 4) + t];
    acc[j] = xv.x * a.x + xv.y * a.y + xv.z * a.z + xv.w * a.w;
  }
#pragma unroll
  for (int j = 0; j < 16; ++j)
#pragma unroll
    for (int s = 32; s > 0; s >>= 1) acc[j] += __shfl_xor(acc[j], s, 64);
  __shared__ float red[16][16];
  const int w = t >> 6, l = t & 63;
  if (l == 0) {
#pragma unroll
    for (int j = 0; j < 16; ++j) red[w][j] = acc[j];
  }
  __syncthreads();
  if (t < 64) {
    ushort v = 0;
    if (t < 16) {
      float s = 0.f;
#pragma unroll
      for (int w2 = 0; w2 < 16; ++w2) s += red[w2][t];
      v = f2h(2.0f * s);
    }
    xa2[m * 64 + t] = v;
  }
}

// kernel 3: K-split fused dequant GEMM (f16 MFMA), LDS-staged A, register q dwords,
// LDS pair-table dequant. Lora K-extension on split 0.
__global__ __launch_bounds__(256, 3)
void gemm_kernel(const uint* __restrict__ pk, const float* __restrict__ am,
                 const ushort* __restrict__ xh, const ushort* __restrict__ lBh,
                 const ushort* __restrict__ xa2, float* __restrict__ dest, int nst) {
  __shared__ ushort Abuf[BM * 64];  // 32 KB, chunk-swizzled
  __shared__ __half2 tbl[256];      // byte -> (nf4[lo], nf4[hi]) unscaled

  const int tid = threadIdx.x;
  const int w = tid >> 6;
  const int l = tid & 63;
  const int chunk = l >> 4;  // 0..3
  const int rlo = l & 15;
  const int split = blockIdx.x / NT2;
  const int ntile = blockIdx.x - split * NT2;
  const int n0 = ntile * BN;
  const int k0 = split * nst * 64;

  tbl[tid & 255] = __halves2half2(__float2half(NF4_TBL[tid & 15]),
                                  __float2half(NF4_TBL[(tid >> 4) & 15]));

  // A deposit geometry (proven R3): issue i covers rows i*32 + w*8 + l/8, swizzled chunk
  const int arow = w * 8 + (l >> 3);
  const int acol = ((l & 7) ^ (l >> 3)) << 3;

  // LDS fragment read offsets, swizzle-matched
  int aoff[2][4];
#pragma unroll
  for (int ks = 0; ks < 2; ++ks) {
    const int cc = ks * 4 + chunk;
#pragma unroll
    for (int mt = 0; mt < 4; ++mt)
      aoff[ks][mt] = (w * 64 + mt * 16 + rlo) * 64 + ((cc ^ (l & 7)) << 3);
  }

  int col[4];
  const char* qp[4];
  const float* amp[4];
#pragma unroll
  for (int nt = 0; nt < 4; ++nt) {
    col[nt] = n0 + nt * 16 + rlo;
    qp[nt] = (const char*)pk + (size_t)col[nt] * (INF / 2) + (k0 >> 1) + chunk * 4;
    amp[nt] = am + (size_t)col[nt] * 64 + (k0 >> 6);
  }

  f32x4 acc[4][4];
#pragma unroll
  for (int mt = 0; mt < 4; ++mt)
#pragma unroll
    for (int nt = 0; nt < 4; ++nt) acc[mt][nt] = (f32x4){0.f, 0.f, 0.f, 0.f};

  for (int s = 0; s < nst; ++s) {
    const int kb = k0 + s * 64;
    // A: 8 async 1KB/wave issues -> 32 KB tile
#pragma unroll
    for (int i = 0; i < 8; ++i) {
      const ushort* g = xh + (size_t)(i * 32 + arow) * INF + kb + acol;
      async_cp16(g, &Abuf[(i * 256 + w * 64) * 8]);
    }
    // q: 8 dwords (4 col-frags x 2 k-substeps) from 22.5MB L2/L3-resident packed codes
    uint qd[4][2];
    __half2 ax2[4];
#pragma unroll
    for (int nt = 0; nt < 4; ++nt) {
      qd[nt][0] = *(const uint*)(qp[nt] + s * 32);
      qd[nt][1] = *(const uint*)(qp[nt] + s * 32 + 16);
      ax2[nt] = __float2half2_rn(amp[nt][s]);
    }
    __syncthreads();
#pragma unroll
    for (int ks = 0; ks < 2; ++ks) {
      f16x8 a[4];
#pragma unroll
      for (int mt = 0; mt < 4; ++mt) a[mt] = *(const f16x8*)&Abuf[aoff[ks][mt]];
      f16x8 b[4];
#pragma unroll
      for (int nt = 0; nt < 4; ++nt) {
        uint dw = qd[nt][ks];
        union { __half2 h[4]; f16x8 v; } u;
        u.h[0] = __hmul2(tbl[dw & 255], ax2[nt]);
        u.h[1] = __hmul2(tbl[(dw >> 8) & 255], ax2[nt]);
        u.h[2] = __hmul2(tbl[(dw >> 16) & 255], ax2[nt]);
        u.h[3] = __hmul2(tbl[dw >> 24], ax2[nt]);
        b[nt] = u.v;
      }
#pragma unroll
      for (int mt = 0; mt < 4; ++mt)
#pragma unroll
        for (int nt = 0; nt < 4; ++nt)
          acc[mt][nt] = __builtin_amdgcn_mfma_f32_16x16x32_f16(a[mt], b[nt], acc[mt][nt], 0, 0, 0);
    }
    __syncthreads();
  }

  if (split == 0) {
    // lora K-extension: k in [0,32) (rank 16 + zero pad); direct register frags
    f16x8 a_l[4], b_l[4];
#pragma unroll
    for (int mt = 0; mt < 4; ++mt)
      a_l[mt] = *(const f16x8*)(xa2 + (size_t)(w * 64 + mt * 16 + rlo) * 64 + chunk * 8);
#pragma unroll
    for (int nt = 0; nt < 4; ++nt)
      b_l[nt] = *(const f16x8*)(lBh + (size_t)col[nt] * 64 + chunk * 8);
#pragma unroll
    for (int mt = 0; mt < 4; ++mt)
#pragma unroll
      for (int nt = 0; nt < 4; ++nt)
        acc[mt][nt] = __builtin_amdgcn_mfma_f32_16x16x32_f16(a_l[mt], b_l[nt], acc[mt][nt], 0, 0, 0);
  }

  // epilogue: C/D layout col=lane&15, row=(lane>>4)*4+reg; each split owns a slice
  float* dst = dest + (size_t)split * TOK * OUTF;
#pragma unroll
  for (int mt = 0; mt < 4; ++mt) {
#pragma unroll
    for (int nt = 0; nt < 4; ++nt) {
      int c = col[nt];
#pragma unroll
      for (int r = 0; r < 4; ++r) {
        int row = w * 64 + mt * 16 + chunk * 4 + r;
        dst[(size_t)row * OUTF + c] = acc[mt][nt][r];
      }
    }
  }
}

// kernel 4: sum K-split partials -> out
__global__ void reduce_kernel(const float4* __restrict__ part, float4* __restrict__ out,
                              int ks) {
  const int QN = TOK * OUTF / 4;
  int i = blockIdx.x * blockDim.x + threadIdx.x;
  if (i < QN) {
    float4 s = part[i];
    for (int s2 = 1; s2 < ks; ++s2) {
      float4 p = part[(size_t)s2 * QN + i];
      s.x += p.x; s.y += p.y; s.z += p.z; s.w += p.w;
    }
    out[i] = s;
  }
}

extern "C" void kernel_launch(void* const* d_in, const int* in_sizes, int n_in,
                              void* d_out, int out_size, void* d_ws, size_t ws_size,
                              hipStream_t stream) {
  const float* x = (const float*)d_in[0];
  const int* qc = (const int*)d_in[1];
  const float* am = (const float*)d_in[2];
  const float* lA = (const float*)d_in[3];
  const float* lB = (const float*)d_in[4];
  float* out = (float*)d_out;

  const size_t off_lB = (size_t)TOK * INF * 2;             // 2.10 MB
  const size_t off_xa2 = off_lB + (size_t)OUTF * 64 * 2;   // +1.41 MB
  const size_t off_pk = off_xa2 + (size_t)TOK * 64 * 2;    // +32 KB  = 3,538,944
  const size_t off_part = off_pk + (size_t)OUTF * INF / 2; // +22.5 MB = 26,083,328
  const size_t part_bytes = (size_t)TOK * OUTF * 4;        // 11.27 MB per split

  ushort* xh = (ushort*)d_ws;
  ushort* lBh = (ushort*)((char*)d_ws + off_lB);
  ushort* xa2 = (ushort*)((char*)d_ws + off_xa2);
  uint* pk = (uint*)((char*)d_ws + off_pk);
  float* part = (float*)((char*)d_ws + off_part);

  int ks = 1;
  if (ws_size >= off_part + 4 * part_bytes) ks = 4;
  else if (ws_size >= off_part + 2 * part_bytes) ks = 2;  // = 48,627,712 B, proven available in R3
  float* dest = (ks == 1) ? out : part;

  prep_kernel<<<4096, 256, 0, stream>>>((const int4*)qc, pk, (const float4*)x,
                                        (ushort4*)xh, (const float4*)lB, (ushort4*)lBh);
  xa_kernel<<<TOK, 1024, 0, stream>>>(x, lA, xa2);
  gemm_kernel<<<NT2 * ks, 256, 0, stream>>>(pk, am, xh, lBh, xa2, dest, 64 / ks);
  if (ks > 1)
    reduce_kernel<<<(TOK * OUTF / 4 + 255) / 256, 256, 0, stream>>>((const float4*)part,
                                                                    (float4*)out, ks);
}